// Round 14
// baseline (275.837 us; speedup 1.0000x reference)
//
#include <hip/hip_runtime.h>

typedef float f32x4 __attribute__((ext_vector_type(4)));
typedef short s16x8 __attribute__((ext_vector_type(8)));

#define MFMA16(a, b, c) __builtin_amdgcn_mfma_f32_16x16x32_bf16((a), (b), (c), 0, 0, 0)

#define B_ 16
#define M_ 6209
#define F_ 256

static __device__ __forceinline__ unsigned short f2bf(float x) {
    unsigned u = __builtin_bit_cast(unsigned, x);
    unsigned r = u + 0x7fffu + ((u >> 16) & 1u);
    return (unsigned short)(r >> 16);
}
static __device__ __forceinline__ float bf2f(unsigned short h) {
    unsigned u = ((unsigned)h) << 16;
    return __builtin_bit_cast(float, u);
}
static __device__ __forceinline__ void split_bf(float x, unsigned short& hi, unsigned short& lo) {
    hi = f2bf(x);
    lo = f2bf(x - bf2f(hi));
}
static __device__ __forceinline__ unsigned cvtpk_bf16(float a, float b) {
    unsigned r;
    asm("v_cvt_pk_bf16_f32 %0, %1, %2" : "=v"(r) : "v"(a), "v"(b));
    return r;   // lo16 = bf(a), hi16 = bf(b)
}

// swizzled u16 index: XOR key (row&7)<<3 spreads banks, preserves 8-u16 chunks
#define SW64(row, k)  ((row) * 64 + ((k) ^ (((row) & 7) << 3)))
#define SW256(row, k) ((row) * 256 + ((k) ^ (((row) & 7) << 3)))

// ---------------- L1: mapped_b (fp32 out + mbp scatter + d) and wcf pack -----------
// blocks 0..1023: wave = one (b, j) row of mapped_b; lane = h.
// blocks 1024..1087: pack Wc B-fragments.
__global__ __launch_bounds__(256) void k_prep(
    const float* __restrict__ inB, const float* __restrict__ Wb, const float* __restrict__ bb,
    const float* __restrict__ Wc, const float* __restrict__ ba,
    unsigned short* __restrict__ wcf, unsigned short* __restrict__ mbp,
    float* __restrict__ mb, float* __restrict__ d) {
    const int blk = blockIdx.x;
    if (blk < 1024) {
        const int b = blk >> 6;
        const int j = (blk & 63) * 4 + (threadIdx.x >> 6);
        const int h = threadIdx.x & 63;
        const float* src = inB + ((size_t)(b * 256 + j)) * 256;
        float s0 = bb[h], s1 = 0.f, s2 = 0.f, s3 = 0.f;
        #pragma unroll 4
        for (int f4 = 0; f4 < 64; ++f4) {
            const f32x4 v = *(const f32x4*)(src + f4 * 4);
            s0 = fmaf(v[0], Wb[(f4 * 4 + 0) * 64 + h], s0);
            s1 = fmaf(v[1], Wb[(f4 * 4 + 1) * 64 + h], s1);
            s2 = fmaf(v[2], Wb[(f4 * 4 + 2) * 64 + h], s2);
            s3 = fmaf(v[3], Wb[(f4 * 4 + 3) * 64 + h], s3);
        }
        const float s = (s0 + s1) + (s2 + s3);
        mb[((size_t)(b * 256 + j)) * 64 + h] = s;
        // mbp (PV A-frag, K=j, col=h): ks=j>>5, nf=h>>4, lane=((j>>3)&3)*16+(h&15), jj=j&7
        const int i2 = (b << 14) | ((j >> 5) << 11) | ((h >> 4) << 9)
                     | (((j >> 3) & 3) << 7) | ((h & 15) << 3) | (j & 7);
        mbp[i2] = f2bf(s);
        // d[b][j] = sum_h ba[h] * s
        float v = ba[h] * s;
        v += __shfl_xor(v, 1);  v += __shfl_xor(v, 2);  v += __shfl_xor(v, 4);
        v += __shfl_xor(v, 8);  v += __shfl_xor(v, 16); v += __shfl_xor(v, 32);
        if (h == 0) d[b * 256 + j] = v;
    } else {
        const int i = (blk - 1024) * 256 + threadIdx.x;   // 0..16383
        int jj = i & 7, lane = (i >> 3) & 63, nf = (i >> 9) & 15, ks = i >> 13;
        int g = lane >> 4, c = lane & 15;
        int h = ks * 32 + g * 8 + jj, f = nf * 16 + c;
        wcf[i] = f2bf(Wc[h * 256 + f]);
    }
}

// ---------------- L2: G^T[j][f] = dot(mb[b][j], Wa[f]) exact fp32, split-scattered --
// grid 4096 = (b, j); 256 threads = f. Scatter target is the QK^T A-fragment index
// (same field-decode pattern as the verified mbp scatter):
//   gf[b][ks=f>>5][jt=j>>4][lane=((f>>3)&3)*16+(j&15)][jj=f&7]
__global__ __launch_bounds__(256) void k_g(
    const float* __restrict__ mb, const float* __restrict__ Wa,
    unsigned short* __restrict__ gfh, unsigned short* __restrict__ gfl) {
    const int blk = blockIdx.x;
    const int b = blk >> 8, j = blk & 255;
    __shared__ float mbS[64];
    const int t = threadIdx.x;
    if (t < 64) mbS[t] = mb[((size_t)(b * 256 + j)) * 64 + t];
    __syncthreads();
    const int f = t;
    const float* wrow = Wa + f * 64;
    float s0 = 0.f, s1 = 0.f, s2 = 0.f, s3 = 0.f;
    #pragma unroll
    for (int h4 = 0; h4 < 16; ++h4) {
        const f32x4 wv = *(const f32x4*)(wrow + h4 * 4);
        const f32x4 mv = *(const f32x4*)(mbS + h4 * 4);
        s0 = fmaf(wv[0], mv[0], s0);
        s1 = fmaf(wv[1], mv[1], s1);
        s2 = fmaf(wv[2], mv[2], s2);
        s3 = fmaf(wv[3], mv[3], s3);
    }
    const float s = (s0 + s1) + (s2 + s3);
    unsigned short hi, lo; split_bf(s, hi, lo);
    const int jt = j >> 4, c = j & 15;
    const int ks = f >> 5, g = (f >> 3) & 3, jj = f & 7;
    const int i = ((((b * 8 + ks) * 16 + jt) * 64 + g * 16 + c) << 3) | jj;
    gfh[i] = hi;
    gfl[i] = lo;
}

// ---------------- L3: main — QK^T from A directly + softmax + PV + projection ------
// grid (98, 16), block 256 = 4 INDEPENDENT waves; wave w owns q-tile t = bx*4+w
// end-to-end. Swapped QK^T: lane holds all 256 logits of q = c spread over 4 lanes
// {c, c+16, c+32, c+48} -> in-register softmax (R4-verified chain).
// NOTE: __syncthreads() between LDS store/read phases is REQUIRED — the u64 stores
// and short8 reads are different types, so TBAA lets the compiler reorder them
// without the barrier (the R12/R13 bug).
__global__ __launch_bounds__(256, 3) void k_main(
    const float* __restrict__ A, const float* __restrict__ d, const float* __restrict__ bc,
    const unsigned short* __restrict__ gfh, const unsigned short* __restrict__ gfl,
    const unsigned short* __restrict__ mbp, const unsigned short* __restrict__ wcf,
    float* __restrict__ out) {
    __shared__ __align__(16) unsigned short pSh[4][4096];   // P^T bf16 [q][j] 8 KB/wave
    __shared__ __align__(16) unsigned short o1S[4][1024];   // out1 bf16 [q][h] 2 KB/wave

    const int b = blockIdx.y;
    const int w = threadIdx.x >> 6, lane = threadIdx.x & 63;
    const int g = lane >> 4, c = lane & 15;
    const int t = blockIdx.x * 4 + w;          // q-tile 0..391 (389+ = all-masked dup)
    const int q0 = t * 16;
    const float SC = 11.541560327f;            // 8 * log2(e)

    // ---- A-tile rows are natively the QK^T B-fragment: load + split once ----
    int arow = q0 + c; if (arow > M_ - 1) arow = M_ - 1;
    const float* abase = A + ((size_t)b * M_ + arow) * F_;
    s16x8 ah[8], al[8];
    #pragma unroll
    for (int ks = 0; ks < 8; ++ks) {
        const f32x4 a0 = *(const f32x4*)(abase + ks * 32 + g * 8);
        const f32x4 a1 = *(const f32x4*)(abase + ks * 32 + g * 8 + 4);
        #pragma unroll
        for (int j = 0; j < 4; ++j) {
            unsigned short hi, lo;
            split_bf(a0[j], hi, lo); ah[ks][j] = (short)hi; al[ks][j] = (short)lo;
            split_bf(a1[j], hi, lo); ah[ks][4 + j] = (short)hi; al[ks][4 + j] = (short)lo;
        }
    }

    // ---- QK^T: S^T[j][q] = G^T @ A^T + d ; acc init from d (f32x4 loads) ----
    f32x4 accST[16];
    #pragma unroll
    for (int jt = 0; jt < 16; ++jt)
        accST[jt] = *(const f32x4*)(d + b * 256 + jt * 16 + g * 4);
    #pragma unroll
    for (int jt = 0; jt < 16; ++jt) {
        #pragma unroll
        for (int ks = 0; ks < 8; ++ks) {
            const size_t off = ((((size_t)b * 8 + ks) * 16 + jt) * 64 + lane) << 3;
            const s16x8 gh = *(const s16x8*)(gfh + off);
            const s16x8 gl = *(const s16x8*)(gfl + off);
            accST[jt] = MFMA16(gh, ah[ks], accST[jt]);
            accST[jt] = MFMA16(gh, al[ks], accST[jt]);
            accST[jt] = MFMA16(gl, ah[ks], accST[jt]);
        }
    }

    // ---- softmax over j for q=c (in-register + lanes c,c+16,c+32,c+48) ----
    f32x4 vm = accST[0];
    #pragma unroll
    for (int jt = 1; jt < 16; ++jt) {
        vm[0] = fmaxf(vm[0], accST[jt][0]); vm[1] = fmaxf(vm[1], accST[jt][1]);
        vm[2] = fmaxf(vm[2], accST[jt][2]); vm[3] = fmaxf(vm[3], accST[jt][3]);
    }
    float m = fmaxf(fmaxf(vm[0], vm[1]), fmaxf(vm[2], vm[3]));
    m = fmaxf(m, __shfl_xor(m, 16));
    m = fmaxf(m, __shfl_xor(m, 32));
    float s = 0.f;
    #pragma unroll
    for (int jt = 0; jt < 16; ++jt) {
        #pragma unroll
        for (int r = 0; r < 4; ++r) {
            const float pv = __builtin_amdgcn_exp2f((accST[jt][r] - m) * SC);
            accST[jt][r] = pv;
            s += pv;
        }
    }
    s += __shfl_xor(s, 16);
    s += __shfl_xor(s, 32);
    const float rinv = 1.f / s;
    // P^T -> LDS [q][j] bf16 (unnormalized; 1/s folded into out1)
    #pragma unroll
    for (int jt = 0; jt < 16; ++jt) {
        const unsigned w0 = cvtpk_bf16(accST[jt][0], accST[jt][1]);
        const unsigned w1 = cvtpk_bf16(accST[jt][2], accST[jt][3]);
        const unsigned long long wv = (unsigned long long)w0 | ((unsigned long long)w1 << 32);
        *(unsigned long long*)&pSh[w][SW256(c, jt * 16 + g * 4)] = wv;
    }
    __syncthreads();   // ORDER pSh u64-stores before s16x8 reads (TBAA hazard)

    // ---- PV: out1^T[h][q] = mfma(A=mbp, B=P^T), K=256 ----
    s16x8 pf[8];
    #pragma unroll
    for (int ks = 0; ks < 8; ++ks)
        pf[ks] = *(const s16x8*)&pSh[w][SW256(c, ks * 32 + g * 8)];
    f32x4 acc1[4];
    #pragma unroll
    for (int ht = 0; ht < 4; ++ht) acc1[ht] = (f32x4){0.f, 0.f, 0.f, 0.f};
    #pragma unroll
    for (int ht = 0; ht < 4; ++ht) {
        #pragma unroll
        for (int ks = 0; ks < 8; ++ks) {
            const size_t off = ((((size_t)b * 8 + ks) * 4 + ht) * 64 + lane) << 3;
            const s16x8 av = *(const s16x8*)(mbp + off);
            acc1[ht] = MFMA16(av, pf[ks], acc1[ht]);
        }
    }
    // out1 (normalized) -> LDS [q][h] bf16; D: row(h)=ht*16+g*4+r, col(q)=c
    #pragma unroll
    for (int ht = 0; ht < 4; ++ht) {
        const unsigned w0 = cvtpk_bf16(acc1[ht][0] * rinv, acc1[ht][1] * rinv);
        const unsigned w1 = cvtpk_bf16(acc1[ht][2] * rinv, acc1[ht][3] * rinv);
        const unsigned long long wv = (unsigned long long)w0 | ((unsigned long long)w1 << 32);
        *(unsigned long long*)&o1S[w][SW64(c, ht * 16 + g * 4)] = wv;
    }
    __syncthreads();   // ORDER o1S u64-stores before s16x8 reads (TBAA hazard)

    // ---- projection: out = out1 @ Wc + bc ----
    s16x8 af[2];
    #pragma unroll
    for (int ks = 0; ks < 2; ++ks)
        af[ks] = *(const s16x8*)&o1S[w][SW64(c, ks * 32 + g * 8)];
    #pragma unroll
    for (int ft = 0; ft < 16; ++ft) {
        const float bv = bc[ft * 16 + c];
        f32x4 acc = (f32x4){bv, bv, bv, bv};
        const s16x8 wb0 = *(const s16x8*)(wcf + (((0 * 16 + ft) * 64 + lane) << 3));
        const s16x8 wb1 = *(const s16x8*)(wcf + (((1 * 16 + ft) * 64 + lane) << 3));
        acc = MFMA16(af[0], wb0, acc);
        acc = MFMA16(af[1], wb1, acc);
        #pragma unroll
        for (int r = 0; r < 4; ++r) {
            const int q = q0 + g * 4 + r;
            if (q < M_) out[((size_t)b * M_ + q) * F_ + ft * 16 + c] = acc[r];
        }
    }
}

extern "C" void kernel_launch(void* const* d_in, const int* in_sizes, int n_in,
                              void* d_out, int out_size, void* d_ws, size_t ws_size,
                              hipStream_t stream) {
    (void)in_sizes; (void)n_in; (void)out_size; (void)ws_size;
    const float* inA = (const float*)d_in[0];
    const float* inB = (const float*)d_in[1];
    const float* Wa  = (const float*)d_in[2];
    const float* ba  = (const float*)d_in[3];
    const float* Wb  = (const float*)d_in[4];
    const float* bb  = (const float*)d_in[5];
    const float* Wc  = (const float*)d_in[6];
    const float* bc  = (const float*)d_in[7];
    float* out = (float*)d_out;

    char* ws = (char*)d_ws;
    unsigned short* wcf  = (unsigned short*)ws;                   //    32,768 B
    unsigned short* mbp  = (unsigned short*)(ws + 32768);         //   524,288 B
    float*          dvec = (float*)(ws + 557056);                 //    16,384 B
    float*          mb   = (float*)(ws + 573440);                 // 1,048,576 B
    unsigned short* gfh  = (unsigned short*)(ws + 1622016);       // 2,097,152 B
    unsigned short* gfl  = (unsigned short*)(ws + 3719168);       // 2,097,152 B (ends 5,816,320)

    hipLaunchKernelGGL(k_prep, dim3(1024 + 64), dim3(256), 0, stream,
                       inB, Wb, bb, Wc, ba, wcf, mbp, mb, dvec);
    hipLaunchKernelGGL(k_g, dim3(4096), dim3(256), 0, stream,
                       mb, Wa, gfh, gfl);
    hipLaunchKernelGGL(k_main, dim3(98, B_), dim3(256), 0, stream,
                       inA, dvec, bc, gfh, gfl, mbp, wcf, out);
}